// Round 9
// baseline (2968.417 us; speedup 1.0000x reference)
//
#include <hip/hip_runtime.h>
#include <cstdint>
#include <cstddef>

// ============================================================================
// LSTMClassifierQuantized: B=64, S=512, H=E=512, 4H=2048, per-tensor int8
// fake-quant on x_t/h/c/W per step. Sequential 512 steps, one grid barrier
// per step (global max|h|, max|c| scales force it).
//
// R9 = R6 (best, 2021us k_main) + micro-opts. R8 post-mortem: scale rec was
// never the critical path; h-visibility chain (store->drain->post->detect->
// cached load) is. R6's single-signal design kept verbatim.
//  - x A-frags live in VGPRs across steps: prefetched for t+1 during t's
//    h-load window. Loop top: the rec probe is the ONLY in-flight load
//    (pure vmcnt(0) check); x-GEMM runs from registers under the probe RT.
//  - fused setup: k_prep = maxw(256 blk) + sx(512) + len/recinit(1);
//    k_pack = wf(256) + xf(4096). Fewer launches, overlapped phases.
//  - self-clear store moved to tid 32 (off tid0's path).
// Carried from R6: 32-slot h ring (uncached 8B stores -> coherence point;
// fresh-address cached float4 loads; buffer_inv every 32 steps), 4rg x 16cg
// partition (same rg per XCD -> L2 dedup of the 32KB h read), weights
// VGPR-resident, exact int8 MFMA GEMM, tagged-rec scale barrier (ring
// depth 4, self-clearing), all-wave 64-lane gather.
// ============================================================================

typedef int v4i __attribute__((ext_vector_type(4)));

#define NB   64
#define SEQ  512
#define HID  512
#define G4   2048
#define NBLK 64
#define NTHR 256
#define HSLOTS 32

// workspace byte offsets
#define OFF_SLOT1   64            // u32[4]: wi, wh, lw abs-max bits
#define OFF_FREC    128           // u32[64] final capmax records (tagged)
#define OFF_REC     384           // u64[4][64] {MH,MC|tag} ring
#define OFF_SX      2432          // f32[512] raw max|x_t|
#define OFF_LEN     4480          // i32[64]
#define OFF_HG      8192          // f32[32 slots][4 rg][16][512] ring
#define ZERO_BYTES  139264        // control + hg slot 0 (zeros = h(0))
#define OFF_HLAST   4202496       // f32[64*512] row-major
#define OFF_WIF     4333568       // v4i[65536] frag-major int8 Wi (1 MB)
#define OFF_WHF     5382144       // v4i[65536]
#define OFF_XF      6430720       // v4i[512*4*8*64] frag-major int8 x (16 MB)
#define WS_NEED     23207936

#define ATOMIC_LD(p)    __hip_atomic_load((p), __ATOMIC_RELAXED, __HIP_MEMORY_SCOPE_AGENT)
#define ATOMIC_ST(p, v) __hip_atomic_store((p), (v), __ATOMIC_RELAXED, __HIP_MEMORY_SCOPE_AGENT)

__device__ __forceinline__ float sigm(float x) {
  return 1.0f / (1.0f + __expf(-x));
}

// magic-number round-to-nearest-even int8 pack (|x*inv| <= 127)
__device__ __forceinline__ int pack4q(float4 v, float inv) {
  union { float f; unsigned u; } a, b, c, d;
  a.f = __builtin_fmaf(v.x, inv, 12582912.0f);   // 1.5 * 2^23
  b.f = __builtin_fmaf(v.y, inv, 12582912.0f);
  c.f = __builtin_fmaf(v.z, inv, 12582912.0f);
  d.f = __builtin_fmaf(v.w, inv, 12582912.0f);
  return (int)((a.u & 0xffu) | ((b.u & 0xffu) << 8) |
               ((c.u & 0xffu) << 16) | ((d.u & 0xffu) << 24));
}

// exact-IEEE-division quantize pack (setup kernels)
__device__ __forceinline__ unsigned packdiv(const float* p, float s) {
  unsigned r = 0;
#pragma unroll
  for (int j = 0; j < 4; j++) {
    int n = (int)rintf(p[j] / s);
    r |= ((unsigned)n & 0xffu) << (8 * j);
  }
  return r;
}

// ------------------------------- setup kernels ------------------------------

// k_prep: blocks [0,256) = weight abs-max; [256,768) = per-t max|x|;
//         block 768 = lengths + rec slot-0 init.
__global__ void k_prep(const int* __restrict__ ids, const int* __restrict__ mask,
                       const float* __restrict__ emb,
                       const float* __restrict__ wi, const float* __restrict__ wh,
                       const float* __restrict__ lw, char* ws) {
  unsigned* ws_u = (unsigned*)ws;
  const int bid = blockIdx.x, tid = threadIdx.x;
  if (bid < 256) {
    float m1 = 0.f, m2 = 0.f, m3 = 0.f;
    int stride = 256 * 256;
    int t0 = bid * 256 + tid;
    for (int i = t0; i < G4 * HID; i += stride) m1 = fmaxf(m1, fabsf(wi[i]));
    for (int i = t0; i < G4 * HID; i += stride) m2 = fmaxf(m2, fabsf(wh[i]));
    for (int i = t0; i < HID; i += stride)      m3 = fmaxf(m3, fabsf(lw[i]));
#pragma unroll
    for (int o = 32; o > 0; o >>= 1) {
      m1 = fmaxf(m1, __shfl_down(m1, o));
      m2 = fmaxf(m2, __shfl_down(m2, o));
      m3 = fmaxf(m3, __shfl_down(m3, o));
    }
    __shared__ float s1[4], s2[4], s3[4];
    int w = tid >> 6, l = tid & 63;
    if (l == 0) { s1[w] = m1; s2[w] = m2; s3[w] = m3; }
    __syncthreads();
    if (tid == 0) {
      m1 = fmaxf(fmaxf(s1[0], s1[1]), fmaxf(s1[2], s1[3]));
      m2 = fmaxf(fmaxf(s2[0], s2[1]), fmaxf(s2[2], s2[3]));
      m3 = fmaxf(fmaxf(s3[0], s3[1]), fmaxf(s3[2], s3[3]));
      atomicMax(&ws_u[OFF_SLOT1 / 4 + 0], __float_as_uint(m1));
      atomicMax(&ws_u[OFF_SLOT1 / 4 + 1], __float_as_uint(m2));
      atomicMax(&ws_u[OFF_SLOT1 / 4 + 2], __float_as_uint(m3));
    }
  } else if (bid < 768) {
    float* sx = (float*)(ws + OFF_SX);
    int t = bid - 256;
    int row = tid >> 2, qu = tid & 3;
    const float* e = emb + (size_t)ids[row * SEQ + t] * HID + qu * 128;
    float m = 0.f;
    for (int i = 0; i < 128; i++) m = fmaxf(m, fabsf(e[i]));
#pragma unroll
    for (int o = 32; o > 0; o >>= 1) m = fmaxf(m, __shfl_down(m, o));
    __shared__ float sm[4];
    if ((tid & 63) == 0) sm[tid >> 6] = m;
    __syncthreads();
    if (tid == 0) sx[t] = fmaxf(fmaxf(sm[0], sm[1]), fmaxf(sm[2], sm[3]));
  } else {
    if (tid < 64) {
      int* len = (int*)(ws + OFF_LEN);
      unsigned long long* rec = (unsigned long long*)(ws + OFF_REC);
      int s = 0;
      for (int i = 0; i < SEQ; i++) s += mask[tid * SEQ + i];
      len[tid] = (s + SEQ - 1) & (SEQ - 1);  // (sum-1) mod 512, jnp wrap
      rec[tid] = 0x8000000000000000ull;      // slot 0 tagged {MH=0,MC=0}
    }
  }
}

// k_pack: blocks [0,256) = weight fragments; [256,4352) = x fragments.
// Weight frags: wf[cg(16)][n(8)][kb(8)][lane(64)] (B-operand, 16x16x64).
//   lcol = n*16+(lane&15): gate g=lcol>>5, unit ul=lcol&31;
//   global col = g*512 + cg*32 + ul.  k = kb*64 + (lane>>4)*16 + 0..15.
// x frags: xf[t(512)][rg(4)][kb(8)][lane(64)] (A-operand for M=16).
//   lane holds A[row=rg*16+(lane&15)][k = kb*64+(lane>>4)*16 + 0..15].
__global__ void k_pack(const int* __restrict__ ids, const float* __restrict__ emb,
                       const float* __restrict__ wi, const float* __restrict__ wh,
                       char* ws) {
  const unsigned* ws_u = (const unsigned*)ws;
  const int bid = blockIdx.x, tid = threadIdx.x;
  if (bid < 256) {
    v4i* wif = (v4i*)(ws + OFF_WIF);
    v4i* whf = (v4i*)(ws + OFF_WHF);
    int t = bid * 256 + tid;                       // 0..65535
    int lane = t & 63, kb = (t >> 6) & 7, n = (t >> 9) & 7, cg = t >> 12;
    int cc = lane & 15, q = lane >> 4;
    int lcol = n * 16 + cc;
    int col = (lcol >> 5) * 512 + cg * 32 + (lcol & 31);
    int k0 = kb * 64 + q * 16;
    float si = fmaxf(__uint_as_float(ws_u[OFF_SLOT1 / 4 + 0]), 1e-8f) / 127.0f;
    float sh = fmaxf(__uint_as_float(ws_u[OFF_SLOT1 / 4 + 1]), 1e-8f) / 127.0f;
    float buf[16];
#pragma unroll
    for (int j = 0; j < 16; j++) buf[j] = wi[(size_t)col * 512 + k0 + j];
    v4i o;
    o[0] = (int)packdiv(buf + 0, si);  o[1] = (int)packdiv(buf + 4, si);
    o[2] = (int)packdiv(buf + 8, si);  o[3] = (int)packdiv(buf + 12, si);
    wif[t] = o;
#pragma unroll
    for (int j = 0; j < 16; j++) buf[j] = wh[(size_t)col * 512 + k0 + j];
    o[0] = (int)packdiv(buf + 0, sh);  o[1] = (int)packdiv(buf + 4, sh);
    o[2] = (int)packdiv(buf + 8, sh);  o[3] = (int)packdiv(buf + 12, sh);
    whf[t] = o;
  } else {
    v4i* xf = (v4i*)(ws + OFF_XF);
    const float* sx = (const float*)(ws + OFF_SX);
    int g = (bid - 256) * 256 + tid;               // 0..1048575
    int lane = g & 63, kb = (g >> 6) & 7, rg = (g >> 9) & 3, t = g >> 11;
    int row = rg * 16 + (lane & 15);
    int k0 = kb * 64 + (lane >> 4) * 16;
    float s = fmaxf(sx[t], 1e-8f) / 127.0f;
    const float* e = emb + (size_t)ids[row * SEQ + t] * HID + k0;
    float buf[16];
#pragma unroll
    for (int j = 0; j < 16; j++) buf[j] = e[j];
    v4i o;
    o[0] = (int)packdiv(buf + 0, s);  o[1] = (int)packdiv(buf + 4, s);
    o[2] = (int)packdiv(buf + 8, s);  o[3] = (int)packdiv(buf + 12, s);
    xf[g] = o;
  }
}

// ------------------------------ persistent kernel ---------------------------

__global__ __launch_bounds__(NTHR, 1) void k_main(
    char* ws, const float* __restrict__ b_inp, const float* __restrict__ b_hid,
    const float* __restrict__ lin_w, const float* __restrict__ lin_b,
    float* __restrict__ out) {
  const int tid  = threadIdx.x;
  const int bk   = blockIdx.x;
  const int lane = tid & 63;
  const int wv   = tid >> 6;               // 4 waves
  const int cc   = lane & 15, qq = lane >> 4;
  const int rg   = (bk & 7) >> 1;          // same rg for all blocks on an XCD
  const int cg   = ((bk >> 3) << 1) | (bk & 1);

  unsigned* slot1 = (unsigned*)(ws + OFF_SLOT1);
  unsigned* frec  = (unsigned*)(ws + OFF_FREC);
  unsigned long long* rec = (unsigned long long*)(ws + OFF_REC);
  const float* sxr = (const float*)(ws + OFF_SX);
  const int* lens  = (const int*)(ws + OFF_LEN);
  float* hg    = (float*)(ws + OFF_HG);
  float* hlast = (float*)(ws + OFF_HLAST);
  const v4i* wifg = (const v4i*)(ws + OFF_WIF);
  const v4i* whfg = (const v4i*)(ws + OFF_WHF);
  const v4i* xfg  = (const v4i*)(ws + OFF_XF);

  __shared__ v4i hf[512];            // 8 KB int8 h A-fragments
  __shared__ float gl[16][132];      // gates [row][lcol], padded
  __shared__ float redh[4], redc[4];

  // weight fragments -> VGPRs for the whole kernel (2 col-tiles per wave)
  const int n0 = wv * 2, n1 = n0 + 1;
  v4i wi0[8], wi1[8], wh0[8], wh1[8];
#pragma unroll
  for (int kb = 0; kb < 8; kb++) {
    wi0[kb] = wifg[((cg * 8 + n0) * 8 + kb) * 64 + lane];
    wi1[kb] = wifg[((cg * 8 + n1) * 8 + kb) * 64 + lane];
    wh0[kb] = whfg[((cg * 8 + n0) * 8 + kb) * 64 + lane];
    wh1[kb] = whfg[((cg * 8 + n1) * 8 + kb) * 64 + lane];
  }
  const int lcol0 = n0 * 16 + cc, lcol1 = n1 * 16 + cc;
  const int col0 = (lcol0 >> 5) * 512 + cg * 32 + (lcol0 & 31);
  const int col1 = (lcol1 >> 5) * 512 + cg * 32 + (lcol1 & 31);
  const float bi0 = b_inp[col0], bh0 = b_hid[col0];
  const float bi1 = b_inp[col1], bh1 = b_hid[col1];
  const float swi = fmaxf(__uint_as_float(slot1[0]), 1e-8f) / 127.0f;
  const float swh = fmaxf(__uint_as_float(slot1[1]), 1e-8f) / 127.0f;

  // h-stage mapping: thread loads row lr2, units [useg*32, +32)
  const int lr2 = tid >> 4, useg = tid & 15;
  const int hidx0 = (useg >> 1) * 64 + ((useg * 2) & 3) * 16 + lr2;
  // cell mapping: thread owns (row lr, local units ul0, ul0+1)
  const int lr = tid >> 4, ul0 = (tid & 15) * 2;
  const int grow = rg * 16 + lr;           // global row
  const int gu = cg * 32 + ul0;            // global unit (8B-aligned pair)
  const int mylen = lens[grow];
  float c0 = 0.0f, c1 = 0.0f, capmax = 0.0f;

  // x A-frags for t=0 preloaded into registers
  v4i xa[8];
#pragma unroll
  for (int kb = 0; kb < 8; kb++)
    xa[kb] = xfg[(size_t)rg * 512 + kb * 64 + lane];

  for (int t = 0; t < SEQ; ++t) {
    // ---- rec probe: the ONLY in-flight load at step start ----
    unsigned long long rv = ATOMIC_LD(&rec[(t & 3) * NBLK + lane]);

    // ---- x-GEMM from registers (hides the probe round-trip) ----
    v4i ax0 = {0,0,0,0}, ax1 = {0,0,0,0};
#pragma unroll
    for (int kb = 0; kb < 8; kb++) {
      ax0 = __builtin_amdgcn_mfma_i32_16x16x64_i8(xa[kb], wi0[kb], ax0, 0, 0, 0);
      ax1 = __builtin_amdgcn_mfma_i32_16x16x64_i8(xa[kb], wi1[kb], ax1, 0, 0, 0);
    }
    const float fx = (fmaxf(sxr[t], 1e-8f) / 127.0f) * swi;
    float xp0[4], xp1[4];
#pragma unroll
    for (int r = 0; r < 4; r++) {
      xp0[r] = (float)ax0[r] * fx + bi0;
      xp1[r] = (float)ax1[r] * fx + bi1;
    }

    // ---- scale barrier: spin until all 64 recs of slot t&3 tagged ----
    while (!__all((int)((long long)rv < 0)))
      rv = ATOMIC_LD(&rec[(t & 3) * NBLK + lane]);
    float mh = __uint_as_float((unsigned)rv);
    float mc = __uint_as_float((unsigned)(rv >> 32) & 0x7fffffffu);
#pragma unroll
    for (int o = 32; o > 0; o >>= 1) {
      mh = fmaxf(mh, __shfl_xor(mh, o));
      mc = fmaxf(mc, __shfl_xor(mc, o));
    }
    if (tid == 32) ATOMIC_ST(&rec[((t + 3) & 3) * NBLK + bk], 0ull); // self-clear

    // h ring slot (t & 31) about to be re-read; drop 32-step-old L2 lines
    if ((t & (HSLOTS - 1)) == 0)
      __builtin_amdgcn_fence(__ATOMIC_ACQUIRE, "agent");

    const float th   = fmaxf(mh, 1e-8f);
    const float invh = 127.0f / th;
    const float fh   = (th / 127.0f) * swh;
    const float tc   = fmaxf(mc, 1e-8f);
    const float scq  = tc / 127.0f;
    const float invc = 127.0f / tc;

    // ---- h: cached float4 loads from fresh ring slot ----
    const float4* hp = (const float4*)(hg +
        ((size_t)(t & (HSLOTS - 1)) * 4 + rg) * (16 * 512) +
        lr2 * 512 + useg * 32);
    float4 f0 = hp[0], f1 = hp[1], f2 = hp[2], f3 = hp[3];
    float4 f4 = hp[4], f5 = hp[5], f6 = hp[6], f7 = hp[7];

    // prefetch x A-frags for t+1 (completes under pack/GEMM/cell/drain)
    if (t + 1 < SEQ) {
      const v4i* xn = xfg + ((size_t)(t + 1) * 4 + rg) * 512;
#pragma unroll
      for (int kb = 0; kb < 8; kb++) xa[kb] = xn[kb * 64 + lane];
    }

    // ---- pack h -> int8 frag-major LDS ----
    {
      v4i pk0, pk1;
      pk0[0] = pack4q(f0, invh); pk0[1] = pack4q(f1, invh);
      pk0[2] = pack4q(f2, invh); pk0[3] = pack4q(f3, invh);
      pk1[0] = pack4q(f4, invh); pk1[1] = pack4q(f5, invh);
      pk1[2] = pack4q(f6, invh); pk1[3] = pack4q(f7, invh);
      hf[hidx0]      = pk0;
      hf[hidx0 + 16] = pk1;
    }
    __syncthreads();   // (A) hf ready

    // ---- h-GEMM: exact int8 MFMA ----
    v4i ah0 = {0,0,0,0}, ah1 = {0,0,0,0};
#pragma unroll
    for (int kb = 0; kb < 8; kb++) {
      v4i a_h = hf[kb * 64 + lane];
      ah0 = __builtin_amdgcn_mfma_i32_16x16x64_i8(a_h, wh0[kb], ah0, 0, 0, 0);
      ah1 = __builtin_amdgcn_mfma_i32_16x16x64_i8(a_h, wh1[kb], ah1, 0, 0, 0);
    }
    // epilogue: mirror np order ((x@WiT + b_inp) + h@WhT) + b_hid
#pragma unroll
    for (int r = 0; r < 4; r++) {
      int lrow = qq * 4 + r;
      gl[lrow][lcol0] = (xp0[r] + (float)ah0[r] * fh) + bh0;
      gl[lrow][lcol1] = (xp1[r] + (float)ah1[r] * fh) + bh1;
    }
    __syncthreads();   // (B) gates ready

    // ---- elementwise LSTM cell (2 cells/thread, c in registers) ----
    float i0 = sigm(gl[lr][ul0]);
    float i1 = sigm(gl[lr][ul0 + 1]);
    float f0g = sigm(gl[lr][32 + ul0]);
    float f1g = sigm(gl[lr][32 + ul0 + 1]);
    float g0 = tanhf(gl[lr][64 + ul0]);
    float g1 = tanhf(gl[lr][64 + ul0 + 1]);
    float o0 = sigm(gl[lr][96 + ul0]);
    float o1 = sigm(gl[lr][96 + ul0 + 1]);
    float cq0 = rintf(c0 * invc) * scq;
    float cq1 = rintf(c1 * invc) * scq;
    float cn0 = f0g * cq0 + i0 * g0;
    float cn1 = f1g * cq1 + i1 * g1;
    float hn0 = o0 * tanhf(cn0);
    float hn1 = o1 * tanhf(cn1);
    c0 = cn0; c1 = cn1;

    // publish h: uncached store into FRESH ring slot (coherence point)
    union { float f[2]; unsigned long long u; } hu;
    hu.f[0] = hn0; hu.f[1] = hn1;
    ATOMIC_ST((unsigned long long*)(hg +
        ((size_t)((t + 1) & (HSLOTS - 1)) * 4 + rg) * (16 * 512) +
        lr * 512 + gu), hu.u);
    if (t == mylen) {
      ATOMIC_ST((unsigned long long*)(hlast + (size_t)grow * 512 + gu), hu.u);
      capmax = fmaxf(capmax, fmaxf(fabsf(hn0), fabsf(hn1)));
    }

    // block abs-max of new h and c
    float mhv = fmaxf(fabsf(hn0), fabsf(hn1));
    float mcv = fmaxf(fabsf(cn0), fabsf(cn1));
#pragma unroll
    for (int o = 32; o > 0; o >>= 1) {
      mhv = fmaxf(mhv, __shfl_down(mhv, o));
      mcv = fmaxf(mcv, __shfl_down(mcv, o));
    }
    if (lane == 0) { redh[wv] = mhv; redc[wv] = mcv; }
    __syncthreads();   // (C) all waves' h stores ACKED (vmcnt0 pre-barrier);
                       //     reds ready. Rec store issued after => any
                       //     observer of the tag sees our h.
    if (tid == 0) {
      float MH = fmaxf(fmaxf(redh[0], redh[1]), fmaxf(redh[2], redh[3]));
      float MC = fmaxf(fmaxf(redc[0], redc[1]), fmaxf(redc[2], redc[3]));
      unsigned long long pv = (unsigned long long)__float_as_uint(MH) |
          ((unsigned long long)(__float_as_uint(MC) | 0x80000000u) << 32);
      ATOMIC_ST(&rec[((t + 1) & 3) * NBLK + bk], pv);   // tagged arrival
    }
  }

  // ---- final round: publish capture max, block 0 computes logits ----
#pragma unroll
  for (int o = 32; o > 0; o >>= 1)
    capmax = fmaxf(capmax, __shfl_down(capmax, o));
  if (lane == 0) redh[wv] = capmax;
  __syncthreads();   // drains hlast stores of all waves too
  if (tid == 0) {
    float CM = fmaxf(fmaxf(redh[0], redh[1]), fmaxf(redh[2], redh[3]));
    ATOMIC_ST(&frec[bk], __float_as_uint(CM) | 0x80000000u);
  }
  if (bk != 0) return;

  if (wv == 0) {
    unsigned fv = ATOMIC_LD(&frec[lane]);
    while (!__all((int)fv < 0)) fv = ATOMIC_LD(&frec[lane]);
    float v = __uint_as_float(fv & 0x7fffffffu);
#pragma unroll
    for (int o = 32; o > 0; o >>= 1) v = fmaxf(v, __shfl_down(v, o));
    if (lane == 0) redh[0] = v;
  }
  __syncthreads();

  {
    float cm = redh[0];
    float tHL = fmaxf(cm, 1e-8f);
    float sHL = tHL / 127.0f, invHL = 127.0f / tHL;
    float tLW = fmaxf(__uint_as_float(slot1[2]), 1e-8f);
    float sLW = tLW / 127.0f, invLW = 127.0f / tLW;
    int b = tid >> 2, seg = tid & 3;
    const unsigned long long* hp2 =
        (const unsigned long long*)(hlast + (size_t)b * 512 + seg * 128);
    float acc = 0.0f;
    for (int j = 0; j < 64; ++j) {
      union { unsigned long long u; float f[2]; } dd;
      dd.u = ATOMIC_LD(hp2 + j);
      float hq0 = rintf(dd.f[0] * invHL) * sHL;
      float wq0 = rintf(lin_w[seg * 128 + 2 * j] * invLW) * sLW;
      acc += hq0 * wq0;
      float hq1 = rintf(dd.f[1] * invHL) * sHL;
      float wq1 = rintf(lin_w[seg * 128 + 2 * j + 1] * invLW) * sLW;
      acc += hq1 * wq1;
    }
    float* fl = &gl[0][0];
    fl[tid] = acc;                 // tid = b*4 + seg
    __syncthreads();
    if (tid < 64) {
      float s = fl[tid * 4] + fl[tid * 4 + 1] + fl[tid * 4 + 2] + fl[tid * 4 + 3];
      out[tid] = s + lin_b[0];
    }
  }
}

// --------------------------------- launch -----------------------------------

extern "C" void kernel_launch(void* const* d_in, const int* in_sizes, int n_in,
                              void* d_out, int out_size, void* d_ws, size_t ws_size,
                              hipStream_t stream) {
  const int*   ids  = (const int*)d_in[0];
  const int*   mask = (const int*)d_in[1];
  const float* emb  = (const float*)d_in[2];
  const float* wi   = (const float*)d_in[3];
  const float* wh   = (const float*)d_in[4];
  const float* binp = (const float*)d_in[5];
  const float* bhid = (const float*)d_in[6];
  const float* lw   = (const float*)d_in[7];
  const float* lb   = (const float*)d_in[8];
  char* ws = (char*)d_ws;
  float* out = (float*)d_out;
  (void)in_sizes; (void)n_in; (void)out_size; (void)ws_size;

  hipMemsetAsync(ws, 0, ZERO_BYTES, stream);
  k_prep<<<769, 256, 0, stream>>>(ids, mask, emb, wi, wh, lw, ws);
  k_pack<<<4352, 256, 0, stream>>>(ids, emb, wi, wh, ws);
  k_main<<<NBLK, NTHR, 0, stream>>>(ws, binp, bhid, lw, lb, out);
}

// Round 10
// 2162.925 us; speedup vs baseline: 1.3724x; 1.3724x over previous
//
#include <hip/hip_runtime.h>
#include <cstdint>
#include <cstddef>

// ============================================================================
// LSTMClassifierQuantized: B=64, S=512, H=E=512, 4H=2048, per-tensor int8
// fake-quant on x_t/h/c/W per step. Sequential 512 steps, one grid barrier
// per step (global max|h|, max|c| scales force it).
//
// R10 = R6 k_main (best verified: 2021us) + double-probe pipelined spin +
// fused setup (R9's k_prep/k_pack, -25us). R9 post-mortem: x prefetch moved
// mid-step put cold x-load latency inside sync(A)'s vmcnt(0) drain =>
// reverted; R6's loop-top placement overlaps x latency with the rec spin.
//  - double-probe spin: keep a 2nd rec probe in flight; sampling interval
//    ~RT/2 instead of RT => avg detect delay ~0.75RT. Safe: slot t&3 is
//    monotone 0->tagged within step t (cleared at t-3, posted once at end
//    of t-1 with final payload).
// Carried from R6: 32-slot h ring (uncached 8B stores -> coherence point;
// fresh-address cached float4 loads; buffer_inv every 32 steps), 4rg x 16cg
// partition (same rg per XCD -> L2 dedup of 32KB h read), weights
// VGPR-resident, exact int8 MFMA GEMM (separate x/h acc), tagged-rec scale
// barrier (ring depth 4, self-clear), h-visibility via rec tag after
// sync(C)'s per-wave vmcnt(0) drain.
// ============================================================================

typedef int v4i __attribute__((ext_vector_type(4)));

#define NB   64
#define SEQ  512
#define HID  512
#define G4   2048
#define NBLK 64
#define NTHR 256
#define HSLOTS 32

// workspace byte offsets
#define OFF_SLOT1   64            // u32[4]: wi, wh, lw abs-max bits
#define OFF_FREC    128           // u32[64] final capmax records (tagged)
#define OFF_REC     384           // u64[4][64] {MH,MC|tag} ring
#define OFF_SX      2432          // f32[512] raw max|x_t|
#define OFF_LEN     4480          // i32[64]
#define OFF_HG      8192          // f32[32 slots][4 rg][16][512] ring
#define ZERO_BYTES  139264        // control + hg slot 0 (zeros = h(0))
#define OFF_HLAST   4202496       // f32[64*512] row-major
#define OFF_WIF     4333568       // v4i[65536] frag-major int8 Wi (1 MB)
#define OFF_WHF     5382144       // v4i[65536]
#define OFF_XF      6430720       // v4i[512*4*8*64] frag-major int8 x (16 MB)
#define WS_NEED     23207936

#define ATOMIC_LD(p)    __hip_atomic_load((p), __ATOMIC_RELAXED, __HIP_MEMORY_SCOPE_AGENT)
#define ATOMIC_ST(p, v) __hip_atomic_store((p), (v), __ATOMIC_RELAXED, __HIP_MEMORY_SCOPE_AGENT)

__device__ __forceinline__ float sigm(float x) {
  return 1.0f / (1.0f + __expf(-x));
}

// magic-number round-to-nearest-even int8 pack (|x*inv| <= 127)
__device__ __forceinline__ int pack4q(float4 v, float inv) {
  union { float f; unsigned u; } a, b, c, d;
  a.f = __builtin_fmaf(v.x, inv, 12582912.0f);   // 1.5 * 2^23
  b.f = __builtin_fmaf(v.y, inv, 12582912.0f);
  c.f = __builtin_fmaf(v.z, inv, 12582912.0f);
  d.f = __builtin_fmaf(v.w, inv, 12582912.0f);
  return (int)((a.u & 0xffu) | ((b.u & 0xffu) << 8) |
               ((c.u & 0xffu) << 16) | ((d.u & 0xffu) << 24));
}

// exact-IEEE-division quantize pack (setup kernels)
__device__ __forceinline__ unsigned packdiv(const float* p, float s) {
  unsigned r = 0;
#pragma unroll
  for (int j = 0; j < 4; j++) {
    int n = (int)rintf(p[j] / s);
    r |= ((unsigned)n & 0xffu) << (8 * j);
  }
  return r;
}

// ------------------------------- setup kernels ------------------------------

// k_prep: blocks [0,256) = weight abs-max; [256,768) = per-t max|x|;
//         block 768 = lengths + rec slot-0 init.
__global__ void k_prep(const int* __restrict__ ids, const int* __restrict__ mask,
                       const float* __restrict__ emb,
                       const float* __restrict__ wi, const float* __restrict__ wh,
                       const float* __restrict__ lw, char* ws) {
  unsigned* ws_u = (unsigned*)ws;
  const int bid = blockIdx.x, tid = threadIdx.x;
  if (bid < 256) {
    float m1 = 0.f, m2 = 0.f, m3 = 0.f;
    int stride = 256 * 256;
    int t0 = bid * 256 + tid;
    for (int i = t0; i < G4 * HID; i += stride) m1 = fmaxf(m1, fabsf(wi[i]));
    for (int i = t0; i < G4 * HID; i += stride) m2 = fmaxf(m2, fabsf(wh[i]));
    for (int i = t0; i < HID; i += stride)      m3 = fmaxf(m3, fabsf(lw[i]));
#pragma unroll
    for (int o = 32; o > 0; o >>= 1) {
      m1 = fmaxf(m1, __shfl_down(m1, o));
      m2 = fmaxf(m2, __shfl_down(m2, o));
      m3 = fmaxf(m3, __shfl_down(m3, o));
    }
    __shared__ float s1[4], s2[4], s3[4];
    int w = tid >> 6, l = tid & 63;
    if (l == 0) { s1[w] = m1; s2[w] = m2; s3[w] = m3; }
    __syncthreads();
    if (tid == 0) {
      m1 = fmaxf(fmaxf(s1[0], s1[1]), fmaxf(s1[2], s1[3]));
      m2 = fmaxf(fmaxf(s2[0], s2[1]), fmaxf(s2[2], s2[3]));
      m3 = fmaxf(fmaxf(s3[0], s3[1]), fmaxf(s3[2], s3[3]));
      atomicMax(&ws_u[OFF_SLOT1 / 4 + 0], __float_as_uint(m1));
      atomicMax(&ws_u[OFF_SLOT1 / 4 + 1], __float_as_uint(m2));
      atomicMax(&ws_u[OFF_SLOT1 / 4 + 2], __float_as_uint(m3));
    }
  } else if (bid < 768) {
    float* sx = (float*)(ws + OFF_SX);
    int t = bid - 256;
    int row = tid >> 2, qu = tid & 3;
    const float* e = emb + (size_t)ids[row * SEQ + t] * HID + qu * 128;
    float m = 0.f;
    for (int i = 0; i < 128; i++) m = fmaxf(m, fabsf(e[i]));
#pragma unroll
    for (int o = 32; o > 0; o >>= 1) m = fmaxf(m, __shfl_down(m, o));
    __shared__ float sm[4];
    if ((tid & 63) == 0) sm[tid >> 6] = m;
    __syncthreads();
    if (tid == 0) sx[t] = fmaxf(fmaxf(sm[0], sm[1]), fmaxf(sm[2], sm[3]));
  } else {
    if (tid < 64) {
      int* len = (int*)(ws + OFF_LEN);
      unsigned long long* rec = (unsigned long long*)(ws + OFF_REC);
      int s = 0;
      for (int i = 0; i < SEQ; i++) s += mask[tid * SEQ + i];
      len[tid] = (s + SEQ - 1) & (SEQ - 1);  // (sum-1) mod 512, jnp wrap
      rec[tid] = 0x8000000000000000ull;      // slot 0 tagged {MH=0,MC=0}
    }
  }
}

// k_pack: blocks [0,256) = weight fragments; [256,4352) = x fragments.
// Weight frags: wf[cg(16)][n(8)][kb(8)][lane(64)] (B-operand, 16x16x64).
//   lcol = n*16+(lane&15): gate g=lcol>>5, unit ul=lcol&31;
//   global col = g*512 + cg*32 + ul.  k = kb*64 + (lane>>4)*16 + 0..15.
// x frags: xf[t(512)][rg(4)][kb(8)][lane(64)] (A-operand for M=16).
//   lane holds A[row=rg*16+(lane&15)][k = kb*64+(lane>>4)*16 + 0..15].
__global__ void k_pack(const int* __restrict__ ids, const float* __restrict__ emb,
                       const float* __restrict__ wi, const float* __restrict__ wh,
                       char* ws) {
  const unsigned* ws_u = (const unsigned*)ws;
  const int bid = blockIdx.x, tid = threadIdx.x;
  if (bid < 256) {
    v4i* wif = (v4i*)(ws + OFF_WIF);
    v4i* whf = (v4i*)(ws + OFF_WHF);
    int t = bid * 256 + tid;                       // 0..65535
    int lane = t & 63, kb = (t >> 6) & 7, n = (t >> 9) & 7, cg = t >> 12;
    int cc = lane & 15, q = lane >> 4;
    int lcol = n * 16 + cc;
    int col = (lcol >> 5) * 512 + cg * 32 + (lcol & 31);
    int k0 = kb * 64 + q * 16;
    float si = fmaxf(__uint_as_float(ws_u[OFF_SLOT1 / 4 + 0]), 1e-8f) / 127.0f;
    float sh = fmaxf(__uint_as_float(ws_u[OFF_SLOT1 / 4 + 1]), 1e-8f) / 127.0f;
    float buf[16];
#pragma unroll
    for (int j = 0; j < 16; j++) buf[j] = wi[(size_t)col * 512 + k0 + j];
    v4i o;
    o[0] = (int)packdiv(buf + 0, si);  o[1] = (int)packdiv(buf + 4, si);
    o[2] = (int)packdiv(buf + 8, si);  o[3] = (int)packdiv(buf + 12, si);
    wif[t] = o;
#pragma unroll
    for (int j = 0; j < 16; j++) buf[j] = wh[(size_t)col * 512 + k0 + j];
    o[0] = (int)packdiv(buf + 0, sh);  o[1] = (int)packdiv(buf + 4, sh);
    o[2] = (int)packdiv(buf + 8, sh);  o[3] = (int)packdiv(buf + 12, sh);
    whf[t] = o;
  } else {
    v4i* xf = (v4i*)(ws + OFF_XF);
    const float* sx = (const float*)(ws + OFF_SX);
    int g = (bid - 256) * 256 + tid;               // 0..1048575
    int lane = g & 63, kb = (g >> 6) & 7, rg = (g >> 9) & 3, t = g >> 11;
    int row = rg * 16 + (lane & 15);
    int k0 = kb * 64 + (lane >> 4) * 16;
    float s = fmaxf(sx[t], 1e-8f) / 127.0f;
    const float* e = emb + (size_t)ids[row * SEQ + t] * HID + k0;
    float buf[16];
#pragma unroll
    for (int j = 0; j < 16; j++) buf[j] = e[j];
    v4i o;
    o[0] = (int)packdiv(buf + 0, s);  o[1] = (int)packdiv(buf + 4, s);
    o[2] = (int)packdiv(buf + 8, s);  o[3] = (int)packdiv(buf + 12, s);
    xf[g] = o;
  }
}

// ------------------------------ persistent kernel ---------------------------

__global__ __launch_bounds__(NTHR, 1) void k_main(
    char* ws, const float* __restrict__ b_inp, const float* __restrict__ b_hid,
    const float* __restrict__ lin_w, const float* __restrict__ lin_b,
    float* __restrict__ out) {
  const int tid  = threadIdx.x;
  const int bk   = blockIdx.x;
  const int lane = tid & 63;
  const int wv   = tid >> 6;               // 4 waves
  const int cc   = lane & 15, qq = lane >> 4;
  const int rg   = (bk & 7) >> 1;          // same rg for all blocks on an XCD
  const int cg   = ((bk >> 3) << 1) | (bk & 1);

  unsigned* slot1 = (unsigned*)(ws + OFF_SLOT1);
  unsigned* frec  = (unsigned*)(ws + OFF_FREC);
  unsigned long long* rec = (unsigned long long*)(ws + OFF_REC);
  const float* sxr = (const float*)(ws + OFF_SX);
  const int* lens  = (const int*)(ws + OFF_LEN);
  float* hg    = (float*)(ws + OFF_HG);
  float* hlast = (float*)(ws + OFF_HLAST);
  const v4i* wifg = (const v4i*)(ws + OFF_WIF);
  const v4i* whfg = (const v4i*)(ws + OFF_WHF);
  const v4i* xfg  = (const v4i*)(ws + OFF_XF);

  __shared__ v4i hf[512];            // 8 KB int8 h A-fragments
  __shared__ float gl[16][132];      // gates [row][lcol], padded
  __shared__ float redh[4], redc[4];

  // weight fragments -> VGPRs for the whole kernel (2 col-tiles per wave)
  const int n0 = wv * 2, n1 = n0 + 1;
  v4i wi0[8], wi1[8], wh0[8], wh1[8];
#pragma unroll
  for (int kb = 0; kb < 8; kb++) {
    wi0[kb] = wifg[((cg * 8 + n0) * 8 + kb) * 64 + lane];
    wi1[kb] = wifg[((cg * 8 + n1) * 8 + kb) * 64 + lane];
    wh0[kb] = whfg[((cg * 8 + n0) * 8 + kb) * 64 + lane];
    wh1[kb] = whfg[((cg * 8 + n1) * 8 + kb) * 64 + lane];
  }
  const int lcol0 = n0 * 16 + cc, lcol1 = n1 * 16 + cc;
  const int col0 = (lcol0 >> 5) * 512 + cg * 32 + (lcol0 & 31);
  const int col1 = (lcol1 >> 5) * 512 + cg * 32 + (lcol1 & 31);
  const float bi0 = b_inp[col0], bh0 = b_hid[col0];
  const float bi1 = b_inp[col1], bh1 = b_hid[col1];
  const float swi = fmaxf(__uint_as_float(slot1[0]), 1e-8f) / 127.0f;
  const float swh = fmaxf(__uint_as_float(slot1[1]), 1e-8f) / 127.0f;

  // h-stage mapping: thread loads row lr2, units [useg*32, +32)
  const int lr2 = tid >> 4, useg = tid & 15;
  const int hidx0 = (useg >> 1) * 64 + ((useg * 2) & 3) * 16 + lr2;
  // cell mapping: thread owns (row lr, local units ul0, ul0+1)
  const int lr = tid >> 4, ul0 = (tid & 15) * 2;
  const int grow = rg * 16 + lr;           // global row
  const int gu = cg * 32 + ul0;            // global unit (8B-aligned pair)
  const int mylen = lens[grow];
  float c0 = 0.0f, c1 = 0.0f, capmax = 0.0f;

  for (int t = 0; t < SEQ; ++t) {
    // ---- x A-frags (cached): issued FIRST (latency overlaps the spin) ----
    const v4i* xt = xfg + ((size_t)t * 4 + rg) * 512;
    v4i xa[8];
#pragma unroll
    for (int kb = 0; kb < 8; kb++) xa[kb] = xt[kb * 64 + lane];

    // first rec probe — round-trip hides under the x-GEMM
    unsigned long long rv = ATOMIC_LD(&rec[(t & 3) * NBLK + lane]);

    // ---- x-GEMM (no barrier dependency) ----
    v4i ax0 = {0,0,0,0}, ax1 = {0,0,0,0};
#pragma unroll
    for (int kb = 0; kb < 8; kb++) {
      ax0 = __builtin_amdgcn_mfma_i32_16x16x64_i8(xa[kb], wi0[kb], ax0, 0, 0, 0);
      ax1 = __builtin_amdgcn_mfma_i32_16x16x64_i8(xa[kb], wi1[kb], ax1, 0, 0, 0);
    }
    const float fx = (fmaxf(sxr[t], 1e-8f) / 127.0f) * swi;
    float xp0[4], xp1[4];
#pragma unroll
    for (int r = 0; r < 4; r++) {
      xp0[r] = (float)ax0[r] * fx + bi0;
      xp1[r] = (float)ax1[r] * fx + bi1;
    }

    // ---- scale barrier: double-probe pipelined spin ----
    // slot t&3 is monotone 0->tagged within step t, payload written once
    // with the tag, so acting on an older probe that passes is safe.
    unsigned long long rv2 = ATOMIC_LD(&rec[(t & 3) * NBLK + lane]);
    while (!__all((int)((long long)rv < 0))) {
      rv = rv2;
      rv2 = ATOMIC_LD(&rec[(t & 3) * NBLK + lane]);
    }
    float mh = __uint_as_float((unsigned)rv);
    float mc = __uint_as_float((unsigned)(rv >> 32) & 0x7fffffffu);
#pragma unroll
    for (int o = 32; o > 0; o >>= 1) {
      mh = fmaxf(mh, __shfl_xor(mh, o));
      mc = fmaxf(mc, __shfl_xor(mc, o));
    }
    if (tid == 0) ATOMIC_ST(&rec[((t + 3) & 3) * NBLK + bk], 0ull);  // self-clear

    // h ring slot (t & 31) about to be re-read; drop 32-step-old L2 lines
    if ((t & (HSLOTS - 1)) == 0)
      __builtin_amdgcn_fence(__ATOMIC_ACQUIRE, "agent");

    const float th   = fmaxf(mh, 1e-8f);
    const float invh = 127.0f / th;
    const float fh   = (th / 127.0f) * swh;
    const float tc   = fmaxf(mc, 1e-8f);
    const float scq  = tc / 127.0f;
    const float invc = 127.0f / tc;

    // ---- h: cached float4 loads from fresh ring slot -> pack -> LDS ----
    {
      const float4* hp = (const float4*)(hg +
          ((size_t)(t & (HSLOTS - 1)) * 4 + rg) * (16 * 512) +
          lr2 * 512 + useg * 32);
      float4 f0 = hp[0], f1 = hp[1], f2 = hp[2], f3 = hp[3];
      float4 f4 = hp[4], f5 = hp[5], f6 = hp[6], f7 = hp[7];
      v4i pk0, pk1;
      pk0[0] = pack4q(f0, invh); pk0[1] = pack4q(f1, invh);
      pk0[2] = pack4q(f2, invh); pk0[3] = pack4q(f3, invh);
      pk1[0] = pack4q(f4, invh); pk1[1] = pack4q(f5, invh);
      pk1[2] = pack4q(f6, invh); pk1[3] = pack4q(f7, invh);
      hf[hidx0]      = pk0;
      hf[hidx0 + 16] = pk1;
    }
    __syncthreads();   // (A) hf ready

    // ---- h-GEMM: exact int8 MFMA ----
    v4i ah0 = {0,0,0,0}, ah1 = {0,0,0,0};
#pragma unroll
    for (int kb = 0; kb < 8; kb++) {
      v4i a_h = hf[kb * 64 + lane];
      ah0 = __builtin_amdgcn_mfma_i32_16x16x64_i8(a_h, wh0[kb], ah0, 0, 0, 0);
      ah1 = __builtin_amdgcn_mfma_i32_16x16x64_i8(a_h, wh1[kb], ah1, 0, 0, 0);
    }
    // epilogue: mirror np order ((x@WiT + b_inp) + h@WhT) + b_hid
#pragma unroll
    for (int r = 0; r < 4; r++) {
      int lrow = qq * 4 + r;
      gl[lrow][lcol0] = (xp0[r] + (float)ah0[r] * fh) + bh0;
      gl[lrow][lcol1] = (xp1[r] + (float)ah1[r] * fh) + bh1;
    }
    __syncthreads();   // (B) gates ready

    // ---- elementwise LSTM cell (2 cells/thread, c in registers) ----
    float i0 = sigm(gl[lr][ul0]);
    float i1 = sigm(gl[lr][ul0 + 1]);
    float f0g = sigm(gl[lr][32 + ul0]);
    float f1g = sigm(gl[lr][32 + ul0 + 1]);
    float g0 = tanhf(gl[lr][64 + ul0]);
    float g1 = tanhf(gl[lr][64 + ul0 + 1]);
    float o0 = sigm(gl[lr][96 + ul0]);
    float o1 = sigm(gl[lr][96 + ul0 + 1]);
    float cq0 = rintf(c0 * invc) * scq;
    float cq1 = rintf(c1 * invc) * scq;
    float cn0 = f0g * cq0 + i0 * g0;
    float cn1 = f1g * cq1 + i1 * g1;
    float hn0 = o0 * tanhf(cn0);
    float hn1 = o1 * tanhf(cn1);
    c0 = cn0; c1 = cn1;

    // publish h: uncached store into FRESH ring slot (coherence point)
    union { float f[2]; unsigned long long u; } hu;
    hu.f[0] = hn0; hu.f[1] = hn1;
    ATOMIC_ST((unsigned long long*)(hg +
        ((size_t)((t + 1) & (HSLOTS - 1)) * 4 + rg) * (16 * 512) +
        lr * 512 + gu), hu.u);
    if (t == mylen) {
      ATOMIC_ST((unsigned long long*)(hlast + (size_t)grow * 512 + gu), hu.u);
      capmax = fmaxf(capmax, fmaxf(fabsf(hn0), fabsf(hn1)));
    }

    // block abs-max of new h and c
    float mhv = fmaxf(fabsf(hn0), fabsf(hn1));
    float mcv = fmaxf(fabsf(cn0), fabsf(cn1));
#pragma unroll
    for (int o = 32; o > 0; o >>= 1) {
      mhv = fmaxf(mhv, __shfl_down(mhv, o));
      mcv = fmaxf(mcv, __shfl_down(mcv, o));
    }
    if (lane == 0) { redh[wv] = mhv; redc[wv] = mcv; }
    __syncthreads();   // (C) all waves' h stores ACKED (vmcnt0 pre-barrier);
                       //     reds ready. Rec store issued after => any
                       //     observer of the tag sees our h.
    if (tid == 0) {
      float MH = fmaxf(fmaxf(redh[0], redh[1]), fmaxf(redh[2], redh[3]));
      float MC = fmaxf(fmaxf(redc[0], redc[1]), fmaxf(redc[2], redc[3]));
      unsigned long long pv = (unsigned long long)__float_as_uint(MH) |
          ((unsigned long long)(__float_as_uint(MC) | 0x80000000u) << 32);
      ATOMIC_ST(&rec[((t + 1) & 3) * NBLK + bk], pv);   // tagged arrival
    }
  }

  // ---- final round: publish capture max, block 0 computes logits ----
#pragma unroll
  for (int o = 32; o > 0; o >>= 1)
    capmax = fmaxf(capmax, __shfl_down(capmax, o));
  if (lane == 0) redh[wv] = capmax;
  __syncthreads();   // drains hlast stores of all waves too
  if (tid == 0) {
    float CM = fmaxf(fmaxf(redh[0], redh[1]), fmaxf(redh[2], redh[3]));
    ATOMIC_ST(&frec[bk], __float_as_uint(CM) | 0x80000000u);
  }
  if (bk != 0) return;

  if (wv == 0) {
    unsigned fv = ATOMIC_LD(&frec[lane]);
    while (!__all((int)fv < 0)) fv = ATOMIC_LD(&frec[lane]);
    float v = __uint_as_float(fv & 0x7fffffffu);
#pragma unroll
    for (int o = 32; o > 0; o >>= 1) v = fmaxf(v, __shfl_down(v, o));
    if (lane == 0) redh[0] = v;
  }
  __syncthreads();

  {
    float cm = redh[0];
    float tHL = fmaxf(cm, 1e-8f);
    float sHL = tHL / 127.0f, invHL = 127.0f / tHL;
    float tLW = fmaxf(__uint_as_float(slot1[2]), 1e-8f);
    float sLW = tLW / 127.0f, invLW = 127.0f / tLW;
    int b = tid >> 2, seg = tid & 3;
    const unsigned long long* hp2 =
        (const unsigned long long*)(hlast + (size_t)b * 512 + seg * 128);
    float acc = 0.0f;
    for (int j = 0; j < 64; ++j) {
      union { unsigned long long u; float f[2]; } dd;
      dd.u = ATOMIC_LD(hp2 + j);
      float hq0 = rintf(dd.f[0] * invHL) * sHL;
      float wq0 = rintf(lin_w[seg * 128 + 2 * j] * invLW) * sLW;
      acc += hq0 * wq0;
      float hq1 = rintf(dd.f[1] * invHL) * sHL;
      float wq1 = rintf(lin_w[seg * 128 + 2 * j + 1] * invLW) * sLW;
      acc += hq1 * wq1;
    }
    float* fl = &gl[0][0];
    fl[tid] = acc;                 // tid = b*4 + seg
    __syncthreads();
    if (tid < 64) {
      float s = fl[tid * 4] + fl[tid * 4 + 1] + fl[tid * 4 + 2] + fl[tid * 4 + 3];
      out[tid] = s + lin_b[0];
    }
  }
}

// --------------------------------- launch -----------------------------------

extern "C" void kernel_launch(void* const* d_in, const int* in_sizes, int n_in,
                              void* d_out, int out_size, void* d_ws, size_t ws_size,
                              hipStream_t stream) {
  const int*   ids  = (const int*)d_in[0];
  const int*   mask = (const int*)d_in[1];
  const float* emb  = (const float*)d_in[2];
  const float* wi   = (const float*)d_in[3];
  const float* wh   = (const float*)d_in[4];
  const float* binp = (const float*)d_in[5];
  const float* bhid = (const float*)d_in[6];
  const float* lw   = (const float*)d_in[7];
  const float* lb   = (const float*)d_in[8];
  char* ws = (char*)d_ws;
  float* out = (float*)d_out;
  (void)in_sizes; (void)n_in; (void)out_size; (void)ws_size;

  hipMemsetAsync(ws, 0, ZERO_BYTES, stream);
  k_prep<<<769, 256, 0, stream>>>(ids, mask, emb, wi, wh, lw, ws);
  k_pack<<<4352, 256, 0, stream>>>(ids, emb, wi, wh, ws);
  k_main<<<NBLK, NTHR, 0, stream>>>(ws, binp, bhid, lw, lb, out);
}